// Round 1
// baseline (258.590 us; speedup 1.0000x reference)
//
#include <hip/hip_runtime.h>
#include <math.h>

// N=32768, M=4096, H=768 fp32.
// out[0..768)=fact_, out[768..1536)=elements_p_.
// Reassociation: (X@W)@y^T == X@(W@y^T) -> matvecs only, never a GEMM.
// Session model (R2-R8): harness-fixed ~120us (incl. per-iter 384MiB ws
// re-poison fill ~59us), ~8.5us/graph-node gap, single-CU gathers ~25us/MB,
// wide (>100-poller) spins catastrophic, narrow (<=8-poller) spins fine.
// R9: structural-minimum 3 nodes. Dependency chain colmax->q | ep->v | fact
// forces exactly 2 kernel boundaries:
//   K1 k_colmax_q: colmax stream + W L3-prefetch + MAGIC-flag arrival
//      (poison-independent, no pre-zeroed counter needed) + last-8 tail
//      computing split-k q = fQ@W (8x768 atomics).
//   K2 k_ep_comb: ep stream + rank-tail (cnt zeroed by K1): per-column
//      combine -> elements_p_ + v = W@ep_ (768 atomics/block vs 147K before).
//   K3 k_fact: unchanged (stream + last-8 + stage-B tail).

#define H 768
#define H4 192
#define PSTRIDE 772   // partial: [0]=m, [1]=L, [2..3]=pad, [4..772)=acc[768]
#define ACC_OFF 4
#define NBLK 256      // stream blocks (1/CU)
#define NTAIL 8
#define TAILB (NBLK - NTAIL)
#define MAGIC 0xA5C3E917u

__device__ __forceinline__ float wave_max(float x) {
#pragma unroll
  for (int o = 32; o; o >>= 1) x = fmaxf(x, __shfl_xor(x, o, 64));
  return x;
}
__device__ __forceinline__ float wave_sum(float x) {
#pragma unroll
  for (int o = 32; o; o >>= 1) x += __shfl_xor(x, o, 64);
  return x;
}
__device__ __forceinline__ float4 f4max(float4 a, float4 b) {
  return make_float4(fmaxf(a.x, b.x), fmaxf(a.y, b.y), fmaxf(a.z, b.z), fmaxf(a.w, b.w));
}

struct SMem {
  float4 sacc[8][H4];  // 24.6 KB wave partials
  float sred[16];
};

// ---- online-softmax weighted row-sum stream -> block partial (R6-proven)
__device__ __forceinline__ void stream_pass(const float4* __restrict__ X4,
                                            const float* __restrict__ wvec,
                                            float* __restrict__ part, int R,
                                            SMem& sm) {
  const int tid = threadIdx.x, lane = tid & 63, wv = tid >> 6;
  float4 wr[3];
#pragma unroll
  for (int j = 0; j < 3; ++j) wr[j] = ((const float4*)wvec)[lane + 64 * j];
  const int nw = NBLK * 8;
  const int gw = blockIdx.x * 8 + wv;
  const int rpw = (R + nw - 1) / nw;
  const int r0 = gw * rpw;
  const int r1 = min(R, r0 + rpw);
  float mrun = -INFINITY, l = 0.f;
  float4 acc[3];
#pragma unroll
  for (int j = 0; j < 3; ++j) acc[j] = make_float4(0.f, 0.f, 0.f, 0.f);
  for (int r = r0; r < r1; ++r) {
    const float4* row = X4 + (size_t)r * H4;
    float4 x[3];
    float s = 0.f;
#pragma unroll
    for (int j = 0; j < 3; ++j) {
      x[j] = row[lane + 64 * j];
      s = fmaf(x[j].x, wr[j].x, s);
      s = fmaf(x[j].y, wr[j].y, s);
      s = fmaf(x[j].z, wr[j].z, s);
      s = fmaf(x[j].w, wr[j].w, s);
    }
    s = wave_sum(s);
    const float mn = fmaxf(mrun, s);
    const float esc = __expf(mrun - mn);  // exp(-inf)=0 on first row
    const float p = __expf(s - mn);
    l = fmaf(l, esc, p);
#pragma unroll
    for (int j = 0; j < 3; ++j) {
      acc[j].x = fmaf(acc[j].x, esc, p * x[j].x);
      acc[j].y = fmaf(acc[j].y, esc, p * x[j].y);
      acc[j].z = fmaf(acc[j].z, esc, p * x[j].z);
      acc[j].w = fmaf(acc[j].w, esc, p * x[j].w);
    }
    mrun = mn;
  }
  if (lane == 0) { sm.sred[wv] = mrun; sm.sred[8 + wv] = l; }
#pragma unroll
  for (int j = 0; j < 3; ++j) sm.sacc[wv][lane + 64 * j] = acc[j];
  __syncthreads();
  if (wv == 0) {
    float gm = -INFINITY;
#pragma unroll
    for (int w2 = 0; w2 < 8; ++w2) gm = fmaxf(gm, sm.sred[w2]);
    float fa[8];
    float L = 0.f;
#pragma unroll
    for (int w2 = 0; w2 < 8; ++w2) {
      const float lw = sm.sred[8 + w2];
      fa[w2] = (lw > 0.f) ? __expf(sm.sred[w2] - gm) : 0.f;
      L = fmaf(fa[w2], lw, L);
    }
    float* pb = part + (size_t)blockIdx.x * PSTRIDE;
#pragma unroll
    for (int j = 0; j < 3; ++j) {
      float4 a = make_float4(0.f, 0.f, 0.f, 0.f);
#pragma unroll
      for (int w2 = 0; w2 < 8; ++w2) {
        const float4 t = sm.sacc[w2][lane + 64 * j];
        a.x = fmaf(fa[w2], t.x, a.x);
        a.y = fmaf(fa[w2], t.y, a.y);
        a.z = fmaf(fa[w2], t.z, a.z);
        a.w = fmaf(fa[w2], t.w, a.w);
      }
      *(float4*)(pb + ACC_OFF + 4 * (lane + 64 * j)) = a;
    }
    if (lane == 0) { pb[0] = gm; pb[1] = L; }
  }
}

// --- K1: colmax partials over fact + W L3-prefetch; block 0 zeroes
// counters + q + v; MAGIC-flag arrival (no pre-zeroed counter needed);
// blocks 248..255 tail: split-k q[h] += fQ[k]*W[k,h] (k-slice of 96).
__global__ __launch_bounds__(192) void k_colmax_q(
    const float4* __restrict__ x4, float4* __restrict__ pmax4, int N,
    unsigned int* __restrict__ cnts, float* __restrict__ q,
    float* __restrict__ v, const float4* __restrict__ W4,
    unsigned int* __restrict__ flags) {
  const int t = threadIdx.x;
  const int b = blockIdx.x;
  if (b == 0) {
    if (t < 8) cnts[t] = 0u;
#pragma unroll
    for (int j = 0; j < 4; ++j) { q[t + 192 * j] = 0.f; v[t + 192 * j] = 0.f; }
  }
  // W prefetch: 256 blocks x 576 float4 = whole W -> L3-warm for both tails.
  {
    float d = 0.f;
    const int base = b * 576;
#pragma unroll
    for (int j = 0; j < 3; ++j) {
      const float4 w = W4[base + t + 192 * j];
      d += w.x + w.y + w.z + w.w;
    }
    asm volatile("" ::"v"(d));  // keep loads live, no store
  }
  // stream colmax
  const int rpb = (N + NBLK - 1) / NBLK;  // 128
  const int n0 = b * rpb;
  const int n1 = min(N, n0 + rpb);
  float4 m = make_float4(-INFINITY, -INFINITY, -INFINITY, -INFINITY);
#pragma unroll 8
  for (int n = n0; n < n1; ++n) m = f4max(m, x4[(size_t)n * H4 + t]);
  pmax4[(size_t)b * H4 + t] = m;

  // arrive: release MAGIC flag (poison-independent; ws re-poisoned per iter)
  __syncthreads();  // drains vmcnt before flag
  if (t == 0) {
    __threadfence();
    __hip_atomic_store(&flags[b], MAGIC, __ATOMIC_RELEASE, __HIP_MEMORY_SCOPE_AGENT);
  }
  if (b < TAILB) return;

  // narrow poll: 8 blocks scan 256 flags
  {
    int ok = 1;
    do {
      ok = 1;
      if (t < 64) {
        ok = (__hip_atomic_load(&flags[t], __ATOMIC_ACQUIRE, __HIP_MEMORY_SCOPE_AGENT) == MAGIC) &&
             (__hip_atomic_load(&flags[t + 64], __ATOMIC_ACQUIRE, __HIP_MEMORY_SCOPE_AGENT) == MAGIC) &&
             (__hip_atomic_load(&flags[t + 128], __ATOMIC_ACQUIRE, __HIP_MEMORY_SCOPE_AGENT) == MAGIC) &&
             (__hip_atomic_load(&flags[t + 192], __ATOMIC_ACQUIRE, __HIP_MEMORY_SCOPE_AGENT) == MAGIC);
      }
      if (__syncthreads_and(ok)) break;
      __builtin_amdgcn_s_sleep(8);
    } while (true);
    __threadfence();
  }

  // ---- tail: k-slice [96*sl, 96*sl+96). fQ-slice over 256 partials, then
  // q[h] += fQ[k]*W[k,h] for all h via atomics (8 adds/address total).
  const int sl = b - TAILB;
  const int k0 = sl * 96;
  const float* pmaxf = (const float*)pmax4;
  __shared__ float sfq2[2][96];
  __shared__ float sfQ[96];
  {
    const int col = t % 96;
    const int pg = t / 96;  // 0..1, 128 partials each
    float mm[8];
#pragma unroll
    for (int u = 0; u < 8; ++u) mm[u] = -INFINITY;
    for (int i = 0; i < 128; i += 8) {
#pragma unroll
      for (int u = 0; u < 8; ++u) {
        const int p = pg + 2 * (i + u);
        mm[u] = fmaxf(mm[u], pmaxf[(size_t)p * H + k0 + col]);
      }
    }
    float mr = mm[0];
#pragma unroll
    for (int u = 1; u < 8; ++u) mr = fmaxf(mr, mm[u]);
    sfq2[pg][col] = mr;
  }
  __syncthreads();
  if (t < 96) sfQ[t] = fmaxf(sfq2[0][t], sfq2[1][t]);
  __syncthreads();
  float4 acc = make_float4(0.f, 0.f, 0.f, 0.f);
#pragma unroll 4
  for (int kk = 0; kk < 96; ++kk) {
    const float f = sfQ[kk];
    const float4 w = W4[(size_t)(k0 + kk) * H4 + t];
    acc.x = fmaf(f, w.x, acc.x);
    acc.y = fmaf(f, w.y, acc.y);
    acc.z = fmaf(f, w.z, acc.z);
    acc.w = fmaf(f, w.w, acc.w);
  }
  atomicAdd(&q[4 * t + 0], acc.x);
  atomicAdd(&q[4 * t + 1], acc.y);
  atomicAdd(&q[4 * t + 2], acc.z);
  atomicAdd(&q[4 * t + 3], acc.w);
}

// --- K2: ep stream (scores ep@q) -> 256 partials; last-8 rank tail:
// per-column softmax combine -> elements_p_ slice (24 float4-cols) + local
// v-contribution (768 atomics/block, 8 adds/address total).
__global__ __launch_bounds__(512) void k_ep_comb(
    const float4* __restrict__ ep4, const float* __restrict__ q,
    float* __restrict__ pm, int M, const float4* __restrict__ W4,
    float4* __restrict__ out_ep, float* __restrict__ v,
    unsigned int* __restrict__ cnt) {
  const int tid = threadIdx.x;
  __shared__ SMem sm;
  stream_pass(ep4, q, pm, M, sm);

  // arrive (cnt zeroed by K1 block 0, one full kernel boundary earlier)
  __shared__ unsigned int s_rank;
  __syncthreads();
  if (tid == 0) {
    __threadfence();
    s_rank = atomicAdd(cnt, 1u);
  }
  __syncthreads();
  const unsigned int rank = s_rank;
  if (rank < (unsigned)TAILB) return;
  if (tid == 0) {
    while (__hip_atomic_load(cnt, __ATOMIC_ACQUIRE, __HIP_MEMORY_SCOPE_AGENT) <
           (unsigned)NBLK)
      __builtin_amdgcn_s_sleep(8);
  }
  __syncthreads();
  __threadfence();

  // ---- tail: slice of 24 float4-cols
  const int sl = (int)rank - TAILB;
  const int cb4 = sl * 24;
  const float* P = pm;
  __shared__ float tm[NBLK], tl[NBLK], te[NBLK];
  __shared__ float sgm, sLt4[4];
  __shared__ float4 sga[21][24];
  __shared__ float4 srr[24];
  if (tid < NBLK) {
    const float* pb = P + (size_t)tid * PSTRIDE;
    tm[tid] = pb[0];
    tl[tid] = pb[1];
  }
  __syncthreads();
  if (tid < 64) {
    float g = fmaxf(fmaxf(tm[tid], tm[tid + 64]), fmaxf(tm[tid + 128], tm[tid + 192]));
    g = wave_max(g);
    if (tid == 0) sgm = g;
  }
  __syncthreads();
  const float gm = sgm;
  if (tid < NBLK) te[tid] = (tl[tid] > 0.f) ? __expf(tm[tid] - gm) : 0.f;
  __syncthreads();
  if (tid < NBLK) {
    float x = te[tid] * tl[tid];
    x = wave_sum(x);
    if ((tid & 63) == 0) sLt4[tid >> 6] = x;
  }
  __syncthreads();
  const float inv = 1.f / (sLt4[0] + sLt4[1] + sLt4[2] + sLt4[3]);
  if (tid < 504) {
    const int c = tid % 24;
    const int pg = tid / 24;  // 0..20
    float4 a = make_float4(0.f, 0.f, 0.f, 0.f);
    for (int p = pg; p < NBLK; p += 21) {
      const float e = te[p];
      const float4 t4 = *(const float4*)(P + (size_t)p * PSTRIDE + ACC_OFF + 4 * (cb4 + c));
      a.x = fmaf(e, t4.x, a.x);
      a.y = fmaf(e, t4.y, a.y);
      a.z = fmaf(e, t4.z, a.z);
      a.w = fmaf(e, t4.w, a.w);
    }
    sga[pg][c] = a;
  }
  __syncthreads();
  if (tid < 24) {
    float4 s = sga[0][tid];
#pragma unroll
    for (int pg = 1; pg < 21; ++pg) {
      const float4 t4 = sga[pg][tid];
      s.x += t4.x; s.y += t4.y; s.z += t4.z; s.w += t4.w;
    }
    const float4 r = make_float4(s.x * inv, s.y * inv, s.z * inv, s.w * inv);
    out_ep[cb4 + tid] = r;
    srr[tid] = r;
  }
  __syncthreads();
  for (int i = tid; i < H; i += 512) {
    float s = 0.f;
#pragma unroll
    for (int c = 0; c < 24; ++c) {
      const float4 w = W4[(size_t)i * H4 + cb4 + c];
      const float4 r = srr[c];
      s = fmaf(w.x, r.x, fmaf(w.y, r.y, fmaf(w.z, r.z, fmaf(w.w, r.w, s))));
    }
    atomicAdd(&v[i], s);
  }
}

// --- K3: fact stream (scores fact@v; fact L3-resident) + narrow hierarchical
// tail: last-8-ranked blocks combine 32 partials each; 8th stage-B arriver
// merges 8 -> out[0..768). (R8-proven, unchanged.)
__global__ __launch_bounds__(512) void k_fact(const float4* __restrict__ X4,
                                              const float* __restrict__ v,
                                              float* __restrict__ pn,
                                              float* __restrict__ pn2, int R,
                                              unsigned int* __restrict__ cntA,
                                              unsigned int* __restrict__ cntB,
                                              float* __restrict__ outp) {
  const int tid = threadIdx.x, lane = tid & 63, wv = tid >> 6;
  __shared__ SMem sm;
  stream_pass(X4, v, pn, R, sm);

  // ---- arrive (syncthreads drains vmcnt before barrier; release fence)
  __shared__ unsigned int s_rank;
  __syncthreads();
  if (tid == 0) {
    __threadfence();
    s_rank = atomicAdd(cntA, 1u);
  }
  __syncthreads();
  const unsigned int rank = s_rank;
  if (rank < (unsigned)(NBLK - 8)) return;

  // narrow spin: at most 8 blocks polling, short skew wait
  if (tid == 0) {
    while (__hip_atomic_load(cntA, __ATOMIC_ACQUIRE, __HIP_MEMORY_SCOPE_AGENT) <
           (unsigned)NBLK)
      __builtin_amdgcn_s_sleep(8);
  }
  __syncthreads();
  __threadfence();

  // ---- stage A: combine 32 partials of our slice -> pn2[slice]
  const int slice = (int)rank - (NBLK - 8);
  const float* Pb = pn + (size_t)slice * 32 * PSTRIDE;
  __shared__ float s32m[32], s32l[32];
  if (tid < 32) {
    s32m[tid] = Pb[(size_t)tid * PSTRIDE];
    s32l[tid] = Pb[(size_t)tid * PSTRIDE + 1];
  }
  __syncthreads();
  float gms = -INFINITY;
#pragma unroll
  for (int b = 0; b < 32; ++b) gms = fmaxf(gms, s32m[b]);
  float4 a[3];
#pragma unroll
  for (int j = 0; j < 3; ++j) a[j] = make_float4(0.f, 0.f, 0.f, 0.f);
  for (int b = wv; b < 32; b += 8) {
    const float e = (s32l[b] > 0.f) ? __expf(s32m[b] - gms) : 0.f;
    const float4* pa = (const float4*)(Pb + (size_t)b * PSTRIDE + ACC_OFF);
#pragma unroll
    for (int j = 0; j < 3; ++j) {
      const float4 t = pa[lane + 64 * j];
      a[j].x = fmaf(e, t.x, a[j].x);
      a[j].y = fmaf(e, t.y, a[j].y);
      a[j].z = fmaf(e, t.z, a[j].z);
      a[j].w = fmaf(e, t.w, a[j].w);
    }
  }
  float lc = 0.f;
  if (tid < 32) lc = ((s32l[tid] > 0.f) ? __expf(s32m[tid] - gms) : 0.f) * s32l[tid];
  lc = wave_sum(lc);  // wave 0 holds the full sum
  __syncthreads();    // sacc reuse guard (stream_pass wrote it)
#pragma unroll
  for (int j = 0; j < 3; ++j) sm.sacc[wv][lane + 64 * j] = a[j];
  if (tid == 0) sm.sred[0] = lc;
  __syncthreads();
  float* qb = pn2 + (size_t)slice * PSTRIDE;
  if (tid < H4) {
    float4 s = sm.sacc[0][tid];
#pragma unroll
    for (int w2 = 1; w2 < 8; ++w2) {
      const float4 t = sm.sacc[w2][tid];
      s.x += t.x; s.y += t.y; s.z += t.z; s.w += t.w;
    }
    *(float4*)(qb + ACC_OFF + 4 * tid) = s;
  }
  if (tid == 0) { qb[0] = gms; qb[1] = sm.sred[0]; }

  // ---- stage B arrive: 8th arriver needs no spin (all 8 already released)
  __syncthreads();
  __shared__ unsigned int s_r2;
  if (tid == 0) {
    __threadfence();
    s_r2 = atomicAdd(cntB, 1u);
  }
  __syncthreads();
  if (s_r2 != 7u) return;
  __threadfence();

  // ---- final: merge 8 L2 partials -> out
  __shared__ float s8m[8], s8l[8];
  if (tid < 8) {
    s8m[tid] = pn2[(size_t)tid * PSTRIDE];
    s8l[tid] = pn2[(size_t)tid * PSTRIDE + 1];
  }
  __syncthreads();
  float gm = -INFINITY;
#pragma unroll
  for (int k = 0; k < 8; ++k) gm = fmaxf(gm, s8m[k]);
  float Lt = 0.f;
#pragma unroll
  for (int k = 0; k < 8; ++k)
    Lt += ((s8l[k] > 0.f) ? __expf(s8m[k] - gm) : 0.f) * s8l[k];
  float4 b[3];
  {
    const int k = wv;  // wave wv handles L2 partial wv
    const float e = (s8l[k] > 0.f) ? __expf(s8m[k] - gm) : 0.f;
    const float4* pa = (const float4*)(pn2 + (size_t)k * PSTRIDE + ACC_OFF);
#pragma unroll
    for (int j = 0; j < 3; ++j) {
      const float4 t = pa[lane + 64 * j];
      b[j] = make_float4(e * t.x, e * t.y, e * t.z, e * t.w);
    }
  }
  __syncthreads();  // sacc reuse guard
#pragma unroll
  for (int j = 0; j < 3; ++j) sm.sacc[wv][lane + 64 * j] = b[j];
  __syncthreads();
  if (tid < H4) {
    float4 s = sm.sacc[0][tid];
#pragma unroll
    for (int w2 = 1; w2 < 8; ++w2) {
      const float4 t = sm.sacc[w2][tid];
      s.x += t.x; s.y += t.y; s.z += t.z; s.w += t.w;
    }
    const float inv = 1.f / Lt;
    ((float4*)outp)[tid] = make_float4(s.x * inv, s.y * inv, s.z * inv, s.w * inv);
  }
}

extern "C" void kernel_launch(void* const* d_in, const int* in_sizes, int n_in,
                              void* d_out, int out_size, void* d_ws, size_t ws_size,
                              hipStream_t stream) {
  const float4* fact4 = (const float4*)d_in[0];  // [N,H]
  const float4* ep4   = (const float4*)d_in[1];  // [M,H]
  const float4* W4    = (const float4*)d_in[2];  // [H,H]
  float* out = (float*)d_out;
  const int N = in_sizes[0] / H;
  const int M = in_sizes[1] / H;

  float* wsf = (float*)d_ws;
  unsigned int* cnts = (unsigned int*)d_ws;        // 8 uints
  float* q     = wsf + 8;                          // 768 (32B-aligned)
  float* v     = wsf + 776;                        // 768
  float* pmaxf = wsf + 1544;                       // 256*768
  float* pm    = wsf + 198152;                     // 256*772 (ep partials)
  float* pn    = wsf + 395784;                     // 256*772 (fact partials)
  float* pn2   = wsf + 593416;                     // 8*772  (L2 partials)
  unsigned int* flags = (unsigned int*)(wsf + 599592);  // 256 uints

  k_colmax_q<<<NBLK, 192, 0, stream>>>(fact4, (float4*)pmaxf, N, cnts, q, v, W4, flags);
  k_ep_comb<<<NBLK, 512, 0, stream>>>(ep4, q, pm, M, W4, (float4*)(out + H), v, cnts + 1);
  k_fact<<<NBLK, 512, 0, stream>>>(fact4, v, pn, pn2, N, cnts + 2, cnts + 3, out);
}

// Round 3
// 244.560 us; speedup vs baseline: 1.0574x; 1.0574x over previous
//
#include <hip/hip_runtime.h>
#include <math.h>

// N=32768, M=4096, H=768 fp32.
// out[0..768)=fact_, out[768..1536)=elements_p_.
// Reassociation: (X@W)@y^T == X@(W@y^T) -> matvecs only, never a GEMM.
// Session model (R2-R9): harness-fixed ~120us (incl. per-iter 384MiB ws
// re-poison fill ~59us), ~8.5us/graph-node gap, single-CU gathers ~25us/MB,
// wide (>100-poller) spins catastrophic, narrow (<=8-poller) spins fine.
// R9 POST-MORTEM: 64-lane ACQUIRE-load poll in K1 tail = buffer_inv per load
// -> polling XCD's whole L2 invalidated continuously -> concurrent streams
// degrade to L3 latency (K1 74us, 732GB/s). R10/R11: poll via RMW
// atomicOr(f,0) (coherent read at L3, NO cache invalidate), single
// __threadfence() after (R10 used __hip_atomic_fence: not in HIP headers).
// 3 nodes (structural minimum for chain colmax->q | ep->v | fact):
//   K1 k_colmax_q: colmax stream + W L3-prefetch + MAGIC flags + last-8
//      fixed-block tail (RMW poll) computing split-k q = fQ@W.
//   K2 k_ep_comb: ep stream + rank-tail (cnt zeroed by K1 blk0): per-column
//      combine -> elements_p_ + v = W@ep_ (rank-based => ~0 poll iters).
//   K3 k_fact: stream + last-8 rank tail + stage-B tail (R8-proven).

#define H 768
#define H4 192
#define PSTRIDE 772   // partial: [0]=m, [1]=L, [2..3]=pad, [4..772)=acc[768]
#define ACC_OFF 4
#define NBLK 256      // stream blocks (1/CU)
#define NTAIL 8
#define TAILB (NBLK - NTAIL)
#define MAGIC 0xA5C3E917u

__device__ __forceinline__ float wave_max(float x) {
#pragma unroll
  for (int o = 32; o; o >>= 1) x = fmaxf(x, __shfl_xor(x, o, 64));
  return x;
}
__device__ __forceinline__ float wave_sum(float x) {
#pragma unroll
  for (int o = 32; o; o >>= 1) x += __shfl_xor(x, o, 64);
  return x;
}
__device__ __forceinline__ float4 f4max(float4 a, float4 b) {
  return make_float4(fmaxf(a.x, b.x), fmaxf(a.y, b.y), fmaxf(a.z, b.z), fmaxf(a.w, b.w));
}

struct SMem {
  float4 sacc[8][H4];  // 24.6 KB wave partials
  float sred[16];
};

// ---- online-softmax weighted row-sum stream -> block partial (R6-proven)
__device__ __forceinline__ void stream_pass(const float4* __restrict__ X4,
                                            const float* __restrict__ wvec,
                                            float* __restrict__ part, int R,
                                            SMem& sm) {
  const int tid = threadIdx.x, lane = tid & 63, wv = tid >> 6;
  float4 wr[3];
#pragma unroll
  for (int j = 0; j < 3; ++j) wr[j] = ((const float4*)wvec)[lane + 64 * j];
  const int nw = NBLK * 8;
  const int gw = blockIdx.x * 8 + wv;
  const int rpw = (R + nw - 1) / nw;
  const int r0 = gw * rpw;
  const int r1 = min(R, r0 + rpw);
  float mrun = -INFINITY, l = 0.f;
  float4 acc[3];
#pragma unroll
  for (int j = 0; j < 3; ++j) acc[j] = make_float4(0.f, 0.f, 0.f, 0.f);
  for (int r = r0; r < r1; ++r) {
    const float4* row = X4 + (size_t)r * H4;
    float4 x[3];
    float s = 0.f;
#pragma unroll
    for (int j = 0; j < 3; ++j) {
      x[j] = row[lane + 64 * j];
      s = fmaf(x[j].x, wr[j].x, s);
      s = fmaf(x[j].y, wr[j].y, s);
      s = fmaf(x[j].z, wr[j].z, s);
      s = fmaf(x[j].w, wr[j].w, s);
    }
    s = wave_sum(s);
    const float mn = fmaxf(mrun, s);
    const float esc = __expf(mrun - mn);  // exp(-inf)=0 on first row
    const float p = __expf(s - mn);
    l = fmaf(l, esc, p);
#pragma unroll
    for (int j = 0; j < 3; ++j) {
      acc[j].x = fmaf(acc[j].x, esc, p * x[j].x);
      acc[j].y = fmaf(acc[j].y, esc, p * x[j].y);
      acc[j].z = fmaf(acc[j].z, esc, p * x[j].z);
      acc[j].w = fmaf(acc[j].w, esc, p * x[j].w);
    }
    mrun = mn;
  }
  if (lane == 0) { sm.sred[wv] = mrun; sm.sred[8 + wv] = l; }
#pragma unroll
  for (int j = 0; j < 3; ++j) sm.sacc[wv][lane + 64 * j] = acc[j];
  __syncthreads();
  if (wv == 0) {
    float gm = -INFINITY;
#pragma unroll
    for (int w2 = 0; w2 < 8; ++w2) gm = fmaxf(gm, sm.sred[w2]);
    float fa[8];
    float L = 0.f;
#pragma unroll
    for (int w2 = 0; w2 < 8; ++w2) {
      const float lw = sm.sred[8 + w2];
      fa[w2] = (lw > 0.f) ? __expf(sm.sred[w2] - gm) : 0.f;
      L = fmaf(fa[w2], lw, L);
    }
    float* pb = part + (size_t)blockIdx.x * PSTRIDE;
#pragma unroll
    for (int j = 0; j < 3; ++j) {
      float4 a = make_float4(0.f, 0.f, 0.f, 0.f);
#pragma unroll
      for (int w2 = 0; w2 < 8; ++w2) {
        const float4 t = sm.sacc[w2][lane + 64 * j];
        a.x = fmaf(fa[w2], t.x, a.x);
        a.y = fmaf(fa[w2], t.y, a.y);
        a.z = fmaf(fa[w2], t.z, a.z);
        a.w = fmaf(fa[w2], t.w, a.w);
      }
      *(float4*)(pb + ACC_OFF + 4 * (lane + 64 * j)) = a;
    }
    if (lane == 0) { pb[0] = gm; pb[1] = L; }
  }
}

// --- K1: colmax partials over fact + W L3-prefetch; block 0 zeroes
// counters + q + v; MAGIC-flag arrival; blocks 248..255 tail (RMW poll,
// NO acquire loads in the loop): split-k q[h] += fQ[k]*W[k,h], k-slice 96.
__global__ __launch_bounds__(192) void k_colmax_q(
    const float4* __restrict__ x4, float4* __restrict__ pmax4, int N,
    unsigned int* __restrict__ cnts, float* __restrict__ q,
    float* __restrict__ v, const float4* __restrict__ W4,
    unsigned int* __restrict__ flags) {
  const int t = threadIdx.x;
  const int b = blockIdx.x;
  if (b == 0) {
    if (t < 8) cnts[t] = 0u;
#pragma unroll
    for (int j = 0; j < 4; ++j) { q[t + 192 * j] = 0.f; v[t + 192 * j] = 0.f; }
  }
  // W prefetch: 256 blocks x 576 float4 = whole W -> L3-warm for both tails.
  // (L3 survives the tail's fence; only L1/L2 get invalidated.)
  {
    float d = 0.f;
    const int base = b * 576;
#pragma unroll
    for (int j = 0; j < 3; ++j) {
      const float4 w = W4[base + t + 192 * j];
      d += w.x + w.y + w.z + w.w;
    }
    asm volatile("" ::"v"(d));  // keep loads live, no store
  }
  // stream colmax
  const int rpb = (N + NBLK - 1) / NBLK;  // 128
  const int n0 = b * rpb;
  const int n1 = min(N, n0 + rpb);
  float4 m = make_float4(-INFINITY, -INFINITY, -INFINITY, -INFINITY);
#pragma unroll 8
  for (int n = n0; n < n1; ++n) m = f4max(m, x4[(size_t)n * H4 + t]);
  pmax4[(size_t)b * H4 + t] = m;

  // arrive: release MAGIC flag (release => wbl2: pmax pushed to L3 first)
  __syncthreads();  // drains vmcnt before flag
  if (t == 0) {
    __hip_atomic_store(&flags[b], MAGIC, __ATOMIC_RELEASE, __HIP_MEMORY_SCOPE_AGENT);
  }
  if (b < TAILB) return;

  // narrow poll, 8 blocks: RMW reads (coherent at L3, no buffer_inv).
  if (t < 64) {
    for (;;) {
      const bool ok =
          (atomicOr(&flags[t], 0u) == MAGIC) &&
          (atomicOr(&flags[t + 64], 0u) == MAGIC) &&
          (atomicOr(&flags[t + 128], 0u) == MAGIC) &&
          (atomicOr(&flags[t + 192], 0u) == MAGIC);
      if (__all(ok)) break;
      __builtin_amdgcn_s_sleep(8);
    }
  }
  __syncthreads();
  // single device-scope fence: invalidate L1/L2 ONCE, then read cached
  __threadfence();

  // ---- tail: k-slice [96*sl, 96*sl+96). float4-wide fQ reduce (8-deep ILP),
  // then q[h] += fQ[k]*W[k,h] via atomics (8 adds/address total).
  const int sl = b - TAILB;
  const int k0 = sl * 96;
  const int c4 = sl * 24;  // float4 col base
  __shared__ float4 sq[8][24];
  __shared__ float sfQ[96];
  {
    const int col = t % 24;
    const int pg = t / 24;  // 0..7
    float4 m4 = make_float4(-INFINITY, -INFINITY, -INFINITY, -INFINITY);
#pragma unroll 8
    for (int i = 0; i < 32; ++i)
      m4 = f4max(m4, pmax4[(size_t)(pg + 8 * i) * H4 + c4 + col]);
    sq[pg][col] = m4;
  }
  __syncthreads();
  if (t < 24) {
    float4 s = sq[0][t];
#pragma unroll
    for (int g = 1; g < 8; ++g) s = f4max(s, sq[g][t]);
    ((float4*)sfQ)[t] = s;
  }
  __syncthreads();
  float4 acc = make_float4(0.f, 0.f, 0.f, 0.f);
#pragma unroll 8
  for (int kk = 0; kk < 96; ++kk) {
    const float f = sfQ[kk];
    const float4 w = W4[(size_t)(k0 + kk) * H4 + t];
    acc.x = fmaf(f, w.x, acc.x);
    acc.y = fmaf(f, w.y, acc.y);
    acc.z = fmaf(f, w.z, acc.z);
    acc.w = fmaf(f, w.w, acc.w);
  }
  atomicAdd(&q[4 * t + 0], acc.x);
  atomicAdd(&q[4 * t + 1], acc.y);
  atomicAdd(&q[4 * t + 2], acc.z);
  atomicAdd(&q[4 * t + 3], acc.w);
}

// --- K2: ep stream (scores ep@q) -> 256 partials; last-8 rank tail:
// per-column softmax combine -> elements_p_ slice (24 float4-cols) + local
// v-contribution (768 atomics/block, 8 adds/address total).
__global__ __launch_bounds__(512) void k_ep_comb(
    const float4* __restrict__ ep4, const float* __restrict__ q,
    float* __restrict__ pm, int M, const float4* __restrict__ W4,
    float4* __restrict__ out_ep, float* __restrict__ v,
    unsigned int* __restrict__ cnt) {
  const int tid = threadIdx.x;
  __shared__ SMem sm;
  stream_pass(ep4, q, pm, M, sm);

  // arrive (cnt zeroed by K1 block 0, one full kernel boundary earlier)
  __shared__ unsigned int s_rank;
  __syncthreads();
  if (tid == 0) {
    __threadfence();
    s_rank = atomicAdd(cnt, 1u);
  }
  __syncthreads();
  const unsigned int rank = s_rank;
  if (rank < (unsigned)TAILB) return;
  if (tid == 0) {
    while (__hip_atomic_load(cnt, __ATOMIC_ACQUIRE, __HIP_MEMORY_SCOPE_AGENT) <
           (unsigned)NBLK)
      __builtin_amdgcn_s_sleep(8);
  }
  __syncthreads();
  __threadfence();

  // ---- tail: slice of 24 float4-cols
  const int sl = (int)rank - TAILB;
  const int cb4 = sl * 24;
  const float* P = pm;
  __shared__ float tm[NBLK], tl[NBLK], te[NBLK];
  __shared__ float sgm, sLt4[4];
  __shared__ float4 sga[21][24];
  __shared__ float4 srr[24];
  if (tid < NBLK) {
    const float* pb = P + (size_t)tid * PSTRIDE;
    tm[tid] = pb[0];
    tl[tid] = pb[1];
  }
  __syncthreads();
  if (tid < 64) {
    float g = fmaxf(fmaxf(tm[tid], tm[tid + 64]), fmaxf(tm[tid + 128], tm[tid + 192]));
    g = wave_max(g);
    if (tid == 0) sgm = g;
  }
  __syncthreads();
  const float gm = sgm;
  if (tid < NBLK) te[tid] = (tl[tid] > 0.f) ? __expf(tm[tid] - gm) : 0.f;
  __syncthreads();
  if (tid < NBLK) {
    float x = te[tid] * tl[tid];
    x = wave_sum(x);
    if ((tid & 63) == 0) sLt4[tid >> 6] = x;
  }
  __syncthreads();
  const float inv = 1.f / (sLt4[0] + sLt4[1] + sLt4[2] + sLt4[3]);
  if (tid < 504) {
    const int c = tid % 24;
    const int pg = tid / 24;  // 0..20
    float4 a = make_float4(0.f, 0.f, 0.f, 0.f);
    for (int p = pg; p < NBLK; p += 21) {
      const float e = te[p];
      const float4 t4 = *(const float4*)(P + (size_t)p * PSTRIDE + ACC_OFF + 4 * (cb4 + c));
      a.x = fmaf(e, t4.x, a.x);
      a.y = fmaf(e, t4.y, a.y);
      a.z = fmaf(e, t4.z, a.z);
      a.w = fmaf(e, t4.w, a.w);
    }
    sga[pg][c] = a;
  }
  __syncthreads();
  if (tid < 24) {
    float4 s = sga[0][tid];
#pragma unroll
    for (int pg = 1; pg < 21; ++pg) {
      const float4 t4 = sga[pg][tid];
      s.x += t4.x; s.y += t4.y; s.z += t4.z; s.w += t4.w;
    }
    const float4 r = make_float4(s.x * inv, s.y * inv, s.z * inv, s.w * inv);
    out_ep[cb4 + tid] = r;
    srr[tid] = r;
  }
  __syncthreads();
  for (int i = tid; i < H; i += 512) {
    float s = 0.f;
#pragma unroll
    for (int c = 0; c < 24; ++c) {
      const float4 w = W4[(size_t)i * H4 + cb4 + c];
      const float4 r = srr[c];
      s = fmaf(w.x, r.x, fmaf(w.y, r.y, fmaf(w.z, r.z, fmaf(w.w, r.w, s))));
    }
    atomicAdd(&v[i], s);
  }
}

// --- K3: fact stream (scores fact@v; fact L3-resident) + narrow hierarchical
// tail: last-8-ranked blocks combine 32 partials each; 8th stage-B arriver
// merges 8 -> out[0..768). (R8-proven, unchanged.)
__global__ __launch_bounds__(512) void k_fact(const float4* __restrict__ X4,
                                              const float* __restrict__ v,
                                              float* __restrict__ pn,
                                              float* __restrict__ pn2, int R,
                                              unsigned int* __restrict__ cntA,
                                              unsigned int* __restrict__ cntB,
                                              float* __restrict__ outp) {
  const int tid = threadIdx.x, lane = tid & 63, wv = tid >> 6;
  __shared__ SMem sm;
  stream_pass(X4, v, pn, R, sm);

  // ---- arrive (syncthreads drains vmcnt before barrier; release fence)
  __shared__ unsigned int s_rank;
  __syncthreads();
  if (tid == 0) {
    __threadfence();
    s_rank = atomicAdd(cntA, 1u);
  }
  __syncthreads();
  const unsigned int rank = s_rank;
  if (rank < (unsigned)(NBLK - 8)) return;

  // narrow spin: at most 8 blocks polling, short skew wait
  if (tid == 0) {
    while (__hip_atomic_load(cntA, __ATOMIC_ACQUIRE, __HIP_MEMORY_SCOPE_AGENT) <
           (unsigned)NBLK)
      __builtin_amdgcn_s_sleep(8);
  }
  __syncthreads();
  __threadfence();

  // ---- stage A: combine 32 partials of our slice -> pn2[slice]
  const int slice = (int)rank - (NBLK - 8);
  const float* Pb = pn + (size_t)slice * 32 * PSTRIDE;
  __shared__ float s32m[32], s32l[32];
  if (tid < 32) {
    s32m[tid] = Pb[(size_t)tid * PSTRIDE];
    s32l[tid] = Pb[(size_t)tid * PSTRIDE + 1];
  }
  __syncthreads();
  float gms = -INFINITY;
#pragma unroll
  for (int b = 0; b < 32; ++b) gms = fmaxf(gms, s32m[b]);
  float4 a[3];
#pragma unroll
  for (int j = 0; j < 3; ++j) a[j] = make_float4(0.f, 0.f, 0.f, 0.f);
  for (int b = wv; b < 32; b += 8) {
    const float e = (s32l[b] > 0.f) ? __expf(s32m[b] - gms) : 0.f;
    const float4* pa = (const float4*)(Pb + (size_t)b * PSTRIDE + ACC_OFF);
#pragma unroll
    for (int j = 0; j < 3; ++j) {
      const float4 t = pa[lane + 64 * j];
      a[j].x = fmaf(e, t.x, a[j].x);
      a[j].y = fmaf(e, t.y, a[j].y);
      a[j].z = fmaf(e, t.z, a[j].z);
      a[j].w = fmaf(e, t.w, a[j].w);
    }
  }
  float lc = 0.f;
  if (tid < 32) lc = ((s32l[tid] > 0.f) ? __expf(s32m[tid] - gms) : 0.f) * s32l[tid];
  lc = wave_sum(lc);  // wave 0 holds the full sum
  __syncthreads();    // sacc reuse guard (stream_pass wrote it)
#pragma unroll
  for (int j = 0; j < 3; ++j) sm.sacc[wv][lane + 64 * j] = a[j];
  if (tid == 0) sm.sred[0] = lc;
  __syncthreads();
  float* qb = pn2 + (size_t)slice * PSTRIDE;
  if (tid < H4) {
    float4 s = sm.sacc[0][tid];
#pragma unroll
    for (int w2 = 1; w2 < 8; ++w2) {
      const float4 t = sm.sacc[w2][tid];
      s.x += t.x; s.y += t.y; s.z += t.z; s.w += t.w;
    }
    *(float4*)(qb + ACC_OFF + 4 * tid) = s;
  }
  if (tid == 0) { qb[0] = gms; qb[1] = sm.sred[0]; }

  // ---- stage B arrive: 8th arriver needs no spin (all 8 already released)
  __syncthreads();
  __shared__ unsigned int s_r2;
  if (tid == 0) {
    __threadfence();
    s_r2 = atomicAdd(cntB, 1u);
  }
  __syncthreads();
  if (s_r2 != 7u) return;
  __threadfence();

  // ---- final: merge 8 L2 partials -> out
  __shared__ float s8m[8], s8l[8];
  if (tid < 8) {
    s8m[tid] = pn2[(size_t)tid * PSTRIDE];
    s8l[tid] = pn2[(size_t)tid * PSTRIDE + 1];
  }
  __syncthreads();
  float gm = -INFINITY;
#pragma unroll
  for (int k = 0; k < 8; ++k) gm = fmaxf(gm, s8m[k]);
  float Lt = 0.f;
#pragma unroll
  for (int k = 0; k < 8; ++k)
    Lt += ((s8l[k] > 0.f) ? __expf(s8m[k] - gm) : 0.f) * s8l[k];
  float4 b[3];
  {
    const int k = wv;  // wave wv handles L2 partial wv
    const float e = (s8l[k] > 0.f) ? __expf(s8m[k] - gm) : 0.f;
    const float4* pa = (const float4*)(pn2 + (size_t)k * PSTRIDE + ACC_OFF);
#pragma unroll
    for (int j = 0; j < 3; ++j) {
      const float4 t = pa[lane + 64 * j];
      b[j] = make_float4(e * t.x, e * t.y, e * t.z, e * t.w);
    }
  }
  __syncthreads();  // sacc reuse guard
#pragma unroll
  for (int j = 0; j < 3; ++j) sm.sacc[wv][lane + 64 * j] = b[j];
  __syncthreads();
  if (tid < H4) {
    float4 s = sm.sacc[0][tid];
#pragma unroll
    for (int w2 = 1; w2 < 8; ++w2) {
      const float4 t = sm.sacc[w2][tid];
      s.x += t.x; s.y += t.y; s.z += t.z; s.w += t.w;
    }
    const float inv = 1.f / Lt;
    ((float4*)outp)[tid] = make_float4(s.x * inv, s.y * inv, s.z * inv, s.w * inv);
  }
}

extern "C" void kernel_launch(void* const* d_in, const int* in_sizes, int n_in,
                              void* d_out, int out_size, void* d_ws, size_t ws_size,
                              hipStream_t stream) {
  const float4* fact4 = (const float4*)d_in[0];  // [N,H]
  const float4* ep4   = (const float4*)d_in[1];  // [M,H]
  const float4* W4    = (const float4*)d_in[2];  // [H,H]
  float* out = (float*)d_out;
  const int N = in_sizes[0] / H;
  const int M = in_sizes[1] / H;

  float* wsf = (float*)d_ws;
  unsigned int* cnts = (unsigned int*)d_ws;        // 8 uints
  float* q     = wsf + 8;                          // 768 (32B-aligned)
  float* v     = wsf + 776;                        // 768
  float* pmaxf = wsf + 1544;                       // 256*768
  float* pm    = wsf + 198152;                     // 256*772 (ep partials)
  float* pn    = wsf + 395784;                     // 256*772 (fact partials)
  float* pn2   = wsf + 593416;                     // 8*772  (L2 partials)
  unsigned int* flags = (unsigned int*)(wsf + 599592);  // 256 uints

  k_colmax_q<<<NBLK, 192, 0, stream>>>(fact4, (float4*)pmaxf, N, cnts, q, v, W4, flags);
  k_ep_comb<<<NBLK, 512, 0, stream>>>(ep4, q, pm, M, W4, (float4*)(out + H), v, cnts + 1);
  k_fact<<<NBLK, 512, 0, stream>>>(fact4, v, pn, pn2, N, cnts + 2, cnts + 3, out);
}